// Round 10
// baseline (186.475 us; speedup 1.0000x reference)
//
#include <hip/hip_runtime.h>
#include <stdint.h>

static constexpr int THREADS = 256;
static constexpr int SCAN_THREADS = 1024;
static constexpr int LOSS_BLOCKS = 512;
static constexpr int CHUNK = 32768;        // one-side chunk: 32768 fp32 = 128 KB LDS
static constexpr int REP_T = 32;           // edge slices (templated fast path)

// fallback (R3-family) constants
static constexpr int CM  = 16384;
static constexpr int CN  = 16384;
static constexpr int CSZ = CM + CN;
static constexpr int MAX_REP = 32;

typedef int   vint4   __attribute__((ext_vector_type(4)));
typedef float vfloat4 __attribute__((ext_vector_type(4)));

// ---------------------------------------------------------------------------
// Phase P: dense gather precompute. g[i]=attr[i]*x[cols[i]],
// h[i]=attr[i]*lam[rows[i]]. Each random gather line-request is issued
// exactly ONCE at full 64-lane density (vs 8x predicated at 1/4 lanes in the
// old fused scan — R8/R5 showed cost is per line-request, so 8x issue was
// the wall). x/lam are L2-resident (512 KB). g/h stores NT (single-writer
// stream; consumed next kernel via L3).
// ---------------------------------------------------------------------------
__global__ __launch_bounds__(THREADS) void kkt_pre(
    const int* __restrict__ rows, const int* __restrict__ cols,
    const float* __restrict__ attr,
    const float* __restrict__ x, const float* __restrict__ lam,
    float* __restrict__ g, float* __restrict__ h, int E) {
  long idx = (long)blockIdx.x * THREADS + threadIdx.x;
  long stride = (long)gridDim.x * THREADS;
  long n4 = (long)E >> 2;
  const vint4*   rows4 = (const vint4*)rows;
  const vint4*   cols4 = (const vint4*)cols;
  const vfloat4* attr4 = (const vfloat4*)attr;
  vfloat4* g4 = (vfloat4*)g;
  vfloat4* h4 = (vfloat4*)h;
  for (long q = idx; q < n4; q += stride) {
    vint4   rr = rows4[q];
    vint4   cc = cols4[q];
    vfloat4 aa = attr4[q];
    vfloat4 gg, hh;
    gg.x = aa.x * x[cc.x];  hh.x = aa.x * lam[rr.x];
    gg.y = aa.y * x[cc.y];  hh.y = aa.y * lam[rr.y];
    gg.z = aa.z * x[cc.z];  hh.z = aa.z * lam[rr.z];
    gg.w = aa.w * x[cc.w];  hh.w = aa.w * lam[rr.w];
    __builtin_nontemporal_store(gg, g4 + q);
    __builtin_nontemporal_store(hh, h4 + q);
  }
  for (long i = (n4 << 2) + idx; i < E; i += stride) {
    float a = attr[i];
    g[i] = a * x[cols[i]];
    h[i] = a * lam[rows[i]];
  }
}

// ---------------------------------------------------------------------------
// Phase S: pure-streaming split scan. Block (q = side-chunk, r = edge slice).
// q < NPr: row-chunk reads (rows, g); else col-chunk reads (cols, h).
// NO gathers — just sequential 8 B/edge streams (was 12 B + gathers) and
// predicated LDS adds (LDS pipe unsaturated: 0 bank conflicts measured).
// bid = q*REP + r => XCD = r%8: all 8 blocks of slice r share one XCD; its
// L2 dedups the redundant stream reads. Streams PLAIN (4x reused; R6: NT on
// reused loads cost +46 µs). Flush NT (single-use).
// ---------------------------------------------------------------------------
template <int REP>
__global__ __launch_bounds__(SCAN_THREADS) void kkt_scan3_t(
    const int* __restrict__ rows, const int* __restrict__ cols,
    const float* __restrict__ g, const float* __restrict__ h,
    float* __restrict__ partial, int E, int NPr) {
  __shared__ float lds[CHUNK];
  const int q = blockIdx.x / REP;
  const int r = blockIdx.x % REP;
  const bool rowside = q < NPr;
  const unsigned base = (unsigned)((rowside ? q : q - NPr) * CHUNK);
  const int*   idxs = rowside ? rows : cols;
  const float* vals = rowside ? g : h;

  vfloat4* l4 = (vfloat4*)lds;
  for (int i = threadIdx.x; i < CHUNK / 4; i += SCAN_THREADS) l4[i] = (vfloat4)(0.0f);
  __syncthreads();

  long per = (((long)E + REP - 1) / REP + 3) & ~3L;
  long e0 = per * r;  if (e0 > E) e0 = E;
  long e1 = e0 + per; if (e1 > E) e1 = E;
  long n4 = (e1 - e0) >> 2;

  const vint4*   idx4 = (const vint4*)(idxs + e0);
  const vfloat4* val4 = (const vfloat4*)(vals + e0);
  const int tid = threadIdx.x;

  for (long qq = tid; qq < n4; qq += SCAN_THREADS) {
    vint4   ii = idx4[qq];
    vfloat4 vv = val4[qq];
    unsigned k0 = (unsigned)ii.x - base;
    unsigned k1 = (unsigned)ii.y - base;
    unsigned k2 = (unsigned)ii.z - base;
    unsigned k3 = (unsigned)ii.w - base;
    if (k0 < (unsigned)CHUNK) unsafeAtomicAdd(&lds[k0], vv.x);
    if (k1 < (unsigned)CHUNK) unsafeAtomicAdd(&lds[k1], vv.y);
    if (k2 < (unsigned)CHUNK) unsafeAtomicAdd(&lds[k2], vv.z);
    if (k3 < (unsigned)CHUNK) unsafeAtomicAdd(&lds[k3], vv.w);
  }
  for (long i = e0 + (n4 << 2) + tid; i < e1; i += SCAN_THREADS) {
    unsigned k = (unsigned)idxs[i] - base;
    if (k < (unsigned)CHUNK) unsafeAtomicAdd(&lds[k], vals[i]);
  }

  __syncthreads();
  vfloat4* d4 = (vfloat4*)(partial + (size_t)blockIdx.x * CHUNK);
  for (int i = threadIdx.x; i < CHUNK / 4; i += SCAN_THREADS)
    __builtin_nontemporal_store(l4[i], d4 + i);
}

// ---------------------------------------------------------------------------
// Loss (templated REP), vectorized; per-block hierarchical reduction, ONE
// non-atomic fp64x4 store per block (same-address fp64 atomics = R5's wall).
// seg_mean_sq(v).sum() == sum(v*v)/per under uniform segment sizes.
// Layout: row slabs [0, NPr*REP), col slabs after, slab = CHUNK fp32.
// ---------------------------------------------------------------------------
template <int REP>
__global__ __launch_bounds__(THREADS) void kkt_loss2_t(
    const float* __restrict__ partial,
    const float* __restrict__ bcat, const float* __restrict__ ccat,
    const float* __restrict__ lam, double* __restrict__ bacc,
    int sum_m, int sum_n, int NPr) {
  long idx = (long)blockIdx.x * THREADS + threadIdx.x;
  long stride = (long)gridDim.x * THREADS;
  long total4 = ((long)sum_m + sum_n) >> 2;
  long m4 = (long)sum_m >> 2;
  const size_t col_off = (size_t)NPr * REP * CHUNK;
  double pr = 0.0, du = 0.0, st = 0.0, cs = 0.0;
  for (long gq = idx; gq < total4; gq += stride) {
    if (gq < m4) {
      int ii = (int)(gq << 2);
      int p = ii / CHUNK, j = ii & (CHUNK - 1);
      const float* b = partial + (size_t)(p * REP) * CHUNK + j;
      vfloat4 ax = (vfloat4)(0.0f);
#pragma unroll
      for (int s = 0; s < REP; ++s)
        ax += __builtin_nontemporal_load((const vfloat4*)(b + (size_t)s * CHUNK));
      vfloat4 bc = *(const vfloat4*)(bcat + ii);
      vfloat4 lv = *(const vfloat4*)(lam + ii);
#pragma unroll
      for (int t = 0; t < 4; ++t) {
        float d  = ax[t] - bc[t];
        float li = lv[t];
        float pp   = d > 0.0f ? d : 0.0f;
        float u    = li < 0.0f ? -li : 0.0f;
        float comp = li * d;
        pr += (double)pp * pp;
        du += (double)u * u;
        cs += (double)comp * comp;
      }
    } else {
      int ii = (int)((gq - m4) << 2);
      int p = ii / CHUNK, j = ii & (CHUNK - 1);
      const float* b = partial + col_off + (size_t)(p * REP) * CHUNK + j;
      vfloat4 at = (vfloat4)(0.0f);
#pragma unroll
      for (int s = 0; s < REP; ++s)
        at += __builtin_nontemporal_load((const vfloat4*)(b + (size_t)s * CHUNK));
      vfloat4 cc = *(const vfloat4*)(ccat + ii);
#pragma unroll
      for (int t = 0; t < 4; ++t) {
        float sv = at[t] + cc[t];
        st += (double)sv * sv;
      }
    }
  }
  for (int off = 32; off > 0; off >>= 1) {
    pr += __shfl_down(pr, off);
    du += __shfl_down(du, off);
    st += __shfl_down(st, off);
    cs += __shfl_down(cs, off);
  }
  __shared__ double sred[THREADS / 64][4];
  const int wv = threadIdx.x >> 6;
  if ((threadIdx.x & 63) == 0) {
    sred[wv][0] = pr; sred[wv][1] = du; sred[wv][2] = st; sred[wv][3] = cs;
  }
  __syncthreads();
  if (threadIdx.x == 0) {
    double a0 = 0, a1 = 0, a2 = 0, a3 = 0;
#pragma unroll
    for (int w = 0; w < THREADS / 64; ++w) {
      a0 += sred[w][0]; a1 += sred[w][1]; a2 += sred[w][2]; a3 += sred[w][3];
    }
    bacc[(size_t)blockIdx.x * 4 + 0] = a0;
    bacc[(size_t)blockIdx.x * 4 + 1] = a1;
    bacc[(size_t)blockIdx.x * 4 + 2] = a2;
    bacc[(size_t)blockIdx.x * 4 + 3] = a3;
  }
}

// ---------------------------------------------------------------------------
// finalize (fast path): sum per-block partials, apply weights. 1 block.
// ---------------------------------------------------------------------------
__global__ __launch_bounds__(THREADS) void kkt_finalize_fast(
    const double* __restrict__ bacc, int nblk,
    const int* __restrict__ Bp, const int* __restrict__ mp,
    const int* __restrict__ np_, float* __restrict__ out) {
  double v0 = 0, v1 = 0, v2 = 0, v3 = 0;
  for (int i = threadIdx.x; i < nblk; i += THREADS) {
    v0 += bacc[(size_t)i * 4 + 0];
    v1 += bacc[(size_t)i * 4 + 1];
    v2 += bacc[(size_t)i * 4 + 2];
    v3 += bacc[(size_t)i * 4 + 3];
  }
  for (int off = 32; off > 0; off >>= 1) {
    v0 += __shfl_down(v0, off);
    v1 += __shfl_down(v1, off);
    v2 += __shfl_down(v2, off);
    v3 += __shfl_down(v3, off);
  }
  __shared__ double sred[THREADS / 64][4];
  const int wv = threadIdx.x >> 6;
  if ((threadIdx.x & 63) == 0) {
    sred[wv][0] = v0; sred[wv][1] = v1; sred[wv][2] = v2; sred[wv][3] = v3;
  }
  __syncthreads();
  if (threadIdx.x == 0) {
    double a0 = 0, a1 = 0, a2 = 0, a3 = 0;
#pragma unroll
    for (int w = 0; w < THREADS / 64; ++w) {
      a0 += sred[w][0]; a1 += sred[w][1]; a2 += sred[w][2]; a3 += sred[w][3];
    }
    double m = (double)mp[0];
    double n = (double)np_[0];
    double B = (double)Bp[0];
    out[0] = (float)((0.1 * (a0 + a1) / m + 0.6 * a2 / n + 0.2 * a3 / m) / B);
  }
}

// ---------------------------------------------------------------------------
// Tier-2 fallback: proven R8 fused split scan (121 µs) if ws can't hold g/h.
// ---------------------------------------------------------------------------
template <int REP>
__global__ __launch_bounds__(SCAN_THREADS) void kkt_scan2_t(
    const int* __restrict__ rows, const int* __restrict__ cols,
    const float* __restrict__ attr,
    const float* __restrict__ x, const float* __restrict__ lam,
    float* __restrict__ partial, int E, int NPr) {
  __shared__ float lds[CHUNK];
  const int q = blockIdx.x / REP;
  const int r = blockIdx.x % REP;
  const bool rowside = q < NPr;
  const unsigned base = (unsigned)((rowside ? q : q - NPr) * CHUNK);
  vfloat4* l4 = (vfloat4*)lds;
  for (int i = threadIdx.x; i < CHUNK / 4; i += SCAN_THREADS) l4[i] = (vfloat4)(0.0f);
  __syncthreads();
  long per = (((long)E + REP - 1) / REP + 3) & ~3L;
  long e0 = per * r;  if (e0 > E) e0 = E;
  long e1 = e0 + per; if (e1 > E) e1 = E;
  long n4 = (e1 - e0) >> 2;
  const vint4*   rows4 = (const vint4*)(rows + e0);
  const vint4*   cols4 = (const vint4*)(cols + e0);
  const vfloat4* attr4 = (const vfloat4*)(attr + e0);
  const int tid = threadIdx.x;
  if (rowside) {
    for (long qq = tid; qq < n4; qq += SCAN_THREADS) {
      vint4 rr = rows4[qq]; vint4 cc = cols4[qq]; vfloat4 aa = attr4[qq];
#define ROW_ACC(RR, CC, AA)                                                  \
      do {                                                                   \
        unsigned k = (unsigned)(RR) - base;                                  \
        if (k < (unsigned)CHUNK) unsafeAtomicAdd(&lds[k], (AA) * x[(CC)]);   \
      } while (0)
      ROW_ACC(rr.x, cc.x, aa.x);
      ROW_ACC(rr.y, cc.y, aa.y);
      ROW_ACC(rr.z, cc.z, aa.z);
      ROW_ACC(rr.w, cc.w, aa.w);
    }
    for (long i = e0 + (n4 << 2) + tid; i < e1; i += SCAN_THREADS) {
      int rv = rows[i], cv = cols[i]; float a = attr[i];
      ROW_ACC(rv, cv, a);
    }
#undef ROW_ACC
  } else {
    for (long qq = tid; qq < n4; qq += SCAN_THREADS) {
      vint4 rr = rows4[qq]; vint4 cc = cols4[qq]; vfloat4 aa = attr4[qq];
#define COL_ACC(RR, CC, AA)                                                  \
      do {                                                                   \
        unsigned k = (unsigned)(CC) - base;                                  \
        if (k < (unsigned)CHUNK) unsafeAtomicAdd(&lds[k], (AA) * lam[(RR)]); \
      } while (0)
      COL_ACC(rr.x, cc.x, aa.x);
      COL_ACC(rr.y, cc.y, aa.y);
      COL_ACC(rr.z, cc.z, aa.z);
      COL_ACC(rr.w, cc.w, aa.w);
    }
    for (long i = e0 + (n4 << 2) + tid; i < e1; i += SCAN_THREADS) {
      int rv = rows[i], cv = cols[i]; float a = attr[i];
      COL_ACC(rv, cv, a);
    }
#undef COL_ACC
  }
  __syncthreads();
  vfloat4* d4 = (vfloat4*)(partial + (size_t)blockIdx.x * CHUNK);
  for (int i = threadIdx.x; i < CHUNK / 4; i += SCAN_THREADS)
    __builtin_nontemporal_store(l4[i], d4 + i);
}

// ---------------------------------------------------------------------------
// Tier-3 fallback (R3 dyn path) for tiny ws.
// ---------------------------------------------------------------------------
__global__ void kkt_init(double* __restrict__ acc, float* __restrict__ out) {
  int t = threadIdx.x;
  if (t < 4) acc[t] = 0.0;
  if (t == 0) out[0] = 0.0f;
}

__global__ __launch_bounds__(SCAN_THREADS) void kkt_scan_dyn(
    const int* __restrict__ rows, const int* __restrict__ cols,
    const float* __restrict__ attr,
    const float* __restrict__ x, const float* __restrict__ lam,
    float* __restrict__ partial, int E, int REP) {
  __shared__ float lds[CSZ];
  const int p = blockIdx.x / REP;
  const int r = blockIdx.x % REP;
  const int baseM = p * CM;
  const int baseN = p * CN;
  vfloat4* l4 = (vfloat4*)lds;
  for (int i = threadIdx.x; i < CSZ / 4; i += SCAN_THREADS) l4[i] = (vfloat4)(0.0f);
  __syncthreads();
  long per = (((long)E + REP - 1) / REP + 3) & ~3L;
  long e0 = per * r;  if (e0 > E) e0 = E;
  long e1 = e0 + per; if (e1 > E) e1 = E;
  int  n4 = (int)((e1 - e0) >> 2);
  const vint4*   rows4 = (const vint4*)(rows + e0);
  const vint4*   cols4 = (const vint4*)(cols + e0);
  const vfloat4* attr4 = (const vfloat4*)(attr + e0);
#define EDGE_ACC(RR, CC, AA)                                                 \
  do {                                                                       \
    unsigned mm = (unsigned)((RR) - baseM);                                  \
    if (mm < (unsigned)CM) unsafeAtomicAdd(&lds[mm], (AA) * x[(CC)]);        \
    unsigned nn = (unsigned)((CC) - baseN);                                  \
    if (nn < (unsigned)CN) unsafeAtomicAdd(&lds[CM + nn], (AA) * lam[(RR)]); \
  } while (0)
  for (int i = threadIdx.x; i < n4; i += SCAN_THREADS) {
    vint4 rr = rows4[i]; vint4 cc = cols4[i]; vfloat4 aa = attr4[i];
    EDGE_ACC(rr.x, cc.x, aa.x);
    EDGE_ACC(rr.y, cc.y, aa.y);
    EDGE_ACC(rr.z, cc.z, aa.z);
    EDGE_ACC(rr.w, cc.w, aa.w);
  }
  for (long i = e0 + ((long)n4 << 2) + threadIdx.x; i < e1; i += SCAN_THREADS) {
    int rr = rows[i], cc = cols[i];
    float aa = attr[i];
    EDGE_ACC(rr, cc, aa);
  }
#undef EDGE_ACC
  __syncthreads();
  vfloat4* d4 = (vfloat4*)(partial + (size_t)(p * REP + r) * CSZ);
  for (int i = threadIdx.x; i < CSZ / 4; i += SCAN_THREADS) d4[i] = l4[i];
}

__global__ __launch_bounds__(THREADS) void kkt_loss_dyn(
    const float* __restrict__ partial,
    const float* __restrict__ bcat, const float* __restrict__ ccat,
    const float* __restrict__ lam, double* __restrict__ acc,
    int sum_m, int sum_n, int REP) {
  int idx = blockIdx.x * blockDim.x + threadIdx.x;
  int stride = gridDim.x * blockDim.x;
  double pr = 0.0, du = 0.0, st = 0.0, cs = 0.0;
  for (int i = idx; i < sum_m; i += stride) {
    int p = i / CM, j = i - p * CM;
    const float* base = partial + (size_t)(p * REP) * CSZ + j;
    float ax = 0.0f;
    for (int rr = 0; rr < REP; ++rr) ax += base[(size_t)rr * CSZ];
    float d  = ax - bcat[i];
    float li = lam[i];
    float pp   = d > 0.0f ? d : 0.0f;
    float u    = li < 0.0f ? -li : 0.0f;
    float comp = li * d;
    pr += (double)pp * pp;
    du += (double)u * u;
    cs += (double)comp * comp;
  }
  for (int i = idx; i < sum_n; i += stride) {
    int p = i / CN, j = i - p * CN;
    const float* base = partial + (size_t)(p * REP) * CSZ + CM + j;
    float at = 0.0f;
    for (int rr = 0; rr < REP; ++rr) at += base[(size_t)rr * CSZ];
    float s = at + ccat[i];
    st += (double)s * s;
  }
  for (int off = 32; off > 0; off >>= 1) {
    pr += __shfl_down(pr, off);
    du += __shfl_down(du, off);
    st += __shfl_down(st, off);
    cs += __shfl_down(cs, off);
  }
  if ((threadIdx.x & 63) == 0) {
    unsafeAtomicAdd(&acc[0], pr);
    unsafeAtomicAdd(&acc[1], du);
    unsafeAtomicAdd(&acc[2], st);
    unsafeAtomicAdd(&acc[3], cs);
  }
}

__global__ void kkt_finalize(const double* __restrict__ acc,
                             const int* __restrict__ Bp,
                             const int* __restrict__ mp,
                             const int* __restrict__ np_,
                             float* __restrict__ out) {
  double m = (double)mp[0];
  double n = (double)np_[0];
  double B = (double)Bp[0];
  double total =
      (0.1 * (acc[0] + acc[1]) / m + 0.6 * acc[2] / n + 0.2 * acc[3] / m) / B;
  out[0] = (float)total;
}

extern "C" void kernel_launch(void* const* d_in, const int* in_sizes, int n_in,
                              void* d_out, int out_size, void* d_ws, size_t ws_size,
                              hipStream_t stream) {
  const float* x    = (const float*)d_in[0];
  const float* lam  = (const float*)d_in[1];
  const int*   rows = (const int*)d_in[2];
  const int*   cols = (const int*)d_in[3];
  const float* attr = (const float*)d_in[4];
  const float* bcat = (const float*)d_in[5];
  const float* ccat = (const float*)d_in[6];
  const int*   Bp   = (const int*)d_in[7];
  const int*   mp   = (const int*)d_in[8];
  const int*   np_  = (const int*)d_in[9];

  const int sum_n = in_sizes[0];
  const int sum_m = in_sizes[1];
  const int E     = in_sizes[2];

  char*   ws   = (char*)d_ws;
  double* acc  = (double*)ws;                    // 32 B (tier-3)
  double* bacc = (double*)(ws + 256);            // LOSS_BLOCKS*4 doubles
  float*  out  = (float*)d_out;

  const int NPr = (sum_m + CHUNK - 1) / CHUNK;
  const int NPc = (sum_n + CHUNK - 1) / CHUNK;
  const int NQ  = NPr + NPc;

  const size_t head = 256 + (size_t)LOSS_BLOCKS * 4 * sizeof(double);
  const size_t part_bytes = (size_t)NQ * REP_T * CHUNK * sizeof(float);
  const size_t gsz = ((size_t)E + 3 & ~(size_t)3) * sizeof(float);

  float* buf = (float*)(ws + head);              // partial slabs
  float* g   = (float*)(ws + head + part_bytes); // [E] a*x[c]
  float* h   = g + (gsz / sizeof(float));        // [E] a*lam[r]

  size_t avail = ws_size > head ? ws_size - head : 0;
  const bool vec_ok = ((sum_m & 3) == 0) && ((sum_n & 3) == 0);
  const size_t need1 = part_bytes + 2 * gsz;     // tier-1: pre + stream scan
  const size_t need2 = part_bytes;               // tier-2: fused scan (R8)

  if (avail >= need1 && vec_ok) {
    int pb = (int)(((long)E / 4 + THREADS - 1) / THREADS);
    if (pb > 2048) pb = 2048;
    kkt_pre<<<pb, THREADS, 0, stream>>>(rows, cols, attr, x, lam, g, h, E);
    kkt_scan3_t<REP_T><<<NQ * REP_T, SCAN_THREADS, 0, stream>>>(
        rows, cols, g, h, buf, E, NPr);
    kkt_loss2_t<REP_T><<<LOSS_BLOCKS, THREADS, 0, stream>>>(
        buf, bcat, ccat, lam, bacc, sum_m, sum_n, NPr);
    kkt_finalize_fast<<<1, THREADS, 0, stream>>>(bacc, LOSS_BLOCKS, Bp, mp,
                                                 np_, out);
  } else if (avail >= need2 && vec_ok) {
    kkt_scan2_t<REP_T><<<NQ * REP_T, SCAN_THREADS, 0, stream>>>(
        rows, cols, attr, x, lam, buf, E, NPr);
    kkt_loss2_t<REP_T><<<LOSS_BLOCKS, THREADS, 0, stream>>>(
        buf, bcat, ccat, lam, bacc, sum_m, sum_n, NPr);
    kkt_finalize_fast<<<1, THREADS, 0, stream>>>(bacc, LOSS_BLOCKS, Bp, mp,
                                                 np_, out);
  } else {
    float* fbuf = (float*)(ws + 64);
    const int NPm = (sum_m + CM - 1) / CM;
    const int NPn = (sum_n + CN - 1) / CN;
    const int NP  = NPm > NPn ? NPm : NPn;
    size_t favail = ws_size > 64 ? ws_size - 64 : 0;
    int REP = (int)(favail / ((size_t)NP * CSZ * sizeof(float)));
    if (REP > MAX_REP) REP = MAX_REP;
    if (REP < 1) REP = 1;
    kkt_init<<<1, 64, 0, stream>>>(acc, out);
    kkt_scan_dyn<<<NP * REP, SCAN_THREADS, 0, stream>>>(rows, cols, attr, x,
                                                        lam, fbuf, E, REP);
    int lw = sum_m > sum_n ? sum_m : sum_n;
    int lb = (lw + THREADS - 1) / THREADS;
    if (lb > 1024) lb = 1024;
    kkt_loss_dyn<<<lb, THREADS, 0, stream>>>(fbuf, bcat, ccat, lam, acc,
                                             sum_m, sum_n, REP);
    kkt_finalize<<<1, 1, 0, stream>>>(acc, Bp, mp, np_, out);
  }
}

// Round 11
// 121.178 us; speedup vs baseline: 1.5389x; 1.5389x over previous
//
#include <hip/hip_runtime.h>
#include <stdint.h>

static constexpr int THREADS = 256;
static constexpr int SCAN_THREADS = 1024;
static constexpr int LOSS_BLOCKS = 512;
static constexpr int CHUNK = 32768;        // one-side chunk: 32768 fp32 = 128 KB LDS
static constexpr int REP_T = 32;           // edge slices (templated fast path)

// fallback (R3-family) constants
static constexpr int CM  = 16384;
static constexpr int CN  = 16384;
static constexpr int CSZ = CM + CN;
static constexpr int MAX_REP = 32;

typedef int   vint4   __attribute__((ext_vector_type(4)));
typedef float vfloat4 __attribute__((ext_vector_type(4)));

// ---------------------------------------------------------------------------
// Split scan (templated REP): block (q = side-chunk, r = edge slice).
// q < NPr: row-chunk: accumulate a*x[c] by row.   q >= NPr: col-chunk:
// accumulate a*lam[r] by col.  MEASURED BEST (R8: 121.6 µs total).
// Why this is the floor (R2/R4/R5/R8/R10 falsifications):
//  - global fp32 atomics: memory-side RMW wall ~21 Gops/s (R1/R2).
//  - HBM-materialized intermediates (binning R4, gather-hoist R10) lose:
//    timed-replay regime has the whole 100 MB input L3-resident, so 8x
//    redundant streams are near-free while new HBM round-trips are not.
//  - instruction-halving (R8) and MLP-unroll (R5): duration pinned =>
//    bound is per-line-request + per-CU return BW, already minimal here.
// bid = q*REP + r => XCD = r%8: all 8 blocks of slice r share one XCD; its
// L2 dedups the redundant edge reads. Edge loads PLAIN (8x reused; R6: NT
// here cost +46 µs). Flush NT (single-use stream).
// ---------------------------------------------------------------------------
template <int REP>
__global__ __launch_bounds__(SCAN_THREADS) void kkt_scan2_t(
    const int* __restrict__ rows, const int* __restrict__ cols,
    const float* __restrict__ attr,
    const float* __restrict__ x, const float* __restrict__ lam,
    float* __restrict__ partial, int E, int NPr) {
  __shared__ float lds[CHUNK];
  const int q = blockIdx.x / REP;
  const int r = blockIdx.x % REP;
  const bool rowside = q < NPr;
  const unsigned base = (unsigned)((rowside ? q : q - NPr) * CHUNK);

  vfloat4* l4 = (vfloat4*)lds;
  for (int i = threadIdx.x; i < CHUNK / 4; i += SCAN_THREADS) l4[i] = (vfloat4)(0.0f);
  __syncthreads();

  long per = (((long)E + REP - 1) / REP + 3) & ~3L;
  long e0 = per * r;  if (e0 > E) e0 = E;
  long e1 = e0 + per; if (e1 > E) e1 = E;
  long n4 = (e1 - e0) >> 2;

  const vint4*   rows4 = (const vint4*)(rows + e0);
  const vint4*   cols4 = (const vint4*)(cols + e0);
  const vfloat4* attr4 = (const vfloat4*)(attr + e0);
  const int tid = threadIdx.x;

  if (rowside) {
    for (long qq = tid; qq < n4; qq += SCAN_THREADS) {
      vint4   rr = rows4[qq];
      vint4   cc = cols4[qq];
      vfloat4 aa = attr4[qq];
#define ROW_ACC(RR, CC, AA)                                                  \
      do {                                                                   \
        unsigned k = (unsigned)(RR) - base;                                  \
        if (k < (unsigned)CHUNK) unsafeAtomicAdd(&lds[k], (AA) * x[(CC)]);   \
      } while (0)
      ROW_ACC(rr.x, cc.x, aa.x);
      ROW_ACC(rr.y, cc.y, aa.y);
      ROW_ACC(rr.z, cc.z, aa.z);
      ROW_ACC(rr.w, cc.w, aa.w);
    }
    for (long i = e0 + (n4 << 2) + tid; i < e1; i += SCAN_THREADS) {
      int rv = rows[i], cv = cols[i];
      float a = attr[i];
      ROW_ACC(rv, cv, a);
    }
#undef ROW_ACC
  } else {
    for (long qq = tid; qq < n4; qq += SCAN_THREADS) {
      vint4   rr = rows4[qq];
      vint4   cc = cols4[qq];
      vfloat4 aa = attr4[qq];
#define COL_ACC(RR, CC, AA)                                                  \
      do {                                                                   \
        unsigned k = (unsigned)(CC) - base;                                  \
        if (k < (unsigned)CHUNK) unsafeAtomicAdd(&lds[k], (AA) * lam[(RR)]); \
      } while (0)
      COL_ACC(rr.x, cc.x, aa.x);
      COL_ACC(rr.y, cc.y, aa.y);
      COL_ACC(rr.z, cc.z, aa.z);
      COL_ACC(rr.w, cc.w, aa.w);
    }
    for (long i = e0 + (n4 << 2) + tid; i < e1; i += SCAN_THREADS) {
      int rv = rows[i], cv = cols[i];
      float a = attr[i];
      COL_ACC(rv, cv, a);
    }
#undef COL_ACC
  }

  __syncthreads();
  vfloat4* d4 = (vfloat4*)(partial + (size_t)blockIdx.x * CHUNK);
  for (int i = threadIdx.x; i < CHUNK / 4; i += SCAN_THREADS)
    __builtin_nontemporal_store(l4[i], d4 + i);
}

// ---------------------------------------------------------------------------
// Loss (templated REP): sum REP replicas per element + loss math; per-block
// hierarchical reduction, ONE non-atomic fp64x4 store per block (same-address
// fp64 atomics were R5's 204 µs wall). Partial reads NT (single-use).
// seg_mean_sq(v).sum() == sum(v*v)/per under uniform segment sizes.
// Layout: row slabs [0, NPr*REP), col slabs after, slab = CHUNK fp32.
// ---------------------------------------------------------------------------
template <int REP>
__global__ __launch_bounds__(THREADS) void kkt_loss2_t(
    const float* __restrict__ partial,
    const float* __restrict__ bcat, const float* __restrict__ ccat,
    const float* __restrict__ lam, double* __restrict__ bacc,
    int sum_m, int sum_n, int NPr) {
  long idx = (long)blockIdx.x * THREADS + threadIdx.x;
  long stride = (long)gridDim.x * THREADS;
  long total = (long)sum_m + sum_n;
  const size_t col_off = (size_t)NPr * REP * CHUNK;
  double pr = 0.0, du = 0.0, st = 0.0, cs = 0.0;
  for (long i = idx; i < total; i += stride) {
    if (i < sum_m) {
      int ii = (int)i;
      int p = ii / CHUNK, j = ii & (CHUNK - 1);
      const float* b = partial + (size_t)(p * REP) * CHUNK + j;
      float ax = 0.0f;
#pragma unroll
      for (int s = 0; s < REP; ++s)
        ax += __builtin_nontemporal_load(b + (size_t)s * CHUNK);
      float d  = ax - bcat[ii];
      float li = lam[ii];
      float pp   = d > 0.0f ? d : 0.0f;
      float u    = li < 0.0f ? -li : 0.0f;
      float comp = li * d;
      pr += (double)pp * pp;
      du += (double)u * u;
      cs += (double)comp * comp;
    } else {
      int ii = (int)(i - sum_m);
      int p = ii / CHUNK, j = ii & (CHUNK - 1);
      const float* b = partial + col_off + (size_t)(p * REP) * CHUNK + j;
      float at = 0.0f;
#pragma unroll
      for (int s = 0; s < REP; ++s)
        at += __builtin_nontemporal_load(b + (size_t)s * CHUNK);
      float sv = at + ccat[ii];
      st += (double)sv * sv;
    }
  }
  for (int off = 32; off > 0; off >>= 1) {
    pr += __shfl_down(pr, off);
    du += __shfl_down(du, off);
    st += __shfl_down(st, off);
    cs += __shfl_down(cs, off);
  }
  __shared__ double sred[THREADS / 64][4];
  const int wv = threadIdx.x >> 6;
  if ((threadIdx.x & 63) == 0) {
    sred[wv][0] = pr; sred[wv][1] = du; sred[wv][2] = st; sred[wv][3] = cs;
  }
  __syncthreads();
  if (threadIdx.x == 0) {
    double a0 = 0, a1 = 0, a2 = 0, a3 = 0;
#pragma unroll
    for (int w = 0; w < THREADS / 64; ++w) {
      a0 += sred[w][0]; a1 += sred[w][1]; a2 += sred[w][2]; a3 += sred[w][3];
    }
    bacc[(size_t)blockIdx.x * 4 + 0] = a0;
    bacc[(size_t)blockIdx.x * 4 + 1] = a1;
    bacc[(size_t)blockIdx.x * 4 + 2] = a2;
    bacc[(size_t)blockIdx.x * 4 + 3] = a3;
  }
}

// ---------------------------------------------------------------------------
// finalize (fast path): sum per-block partials, apply weights. 1 block.
// ---------------------------------------------------------------------------
__global__ __launch_bounds__(THREADS) void kkt_finalize_fast(
    const double* __restrict__ bacc, int nblk,
    const int* __restrict__ Bp, const int* __restrict__ mp,
    const int* __restrict__ np_, float* __restrict__ out) {
  double v0 = 0, v1 = 0, v2 = 0, v3 = 0;
  for (int i = threadIdx.x; i < nblk; i += THREADS) {
    v0 += bacc[(size_t)i * 4 + 0];
    v1 += bacc[(size_t)i * 4 + 1];
    v2 += bacc[(size_t)i * 4 + 2];
    v3 += bacc[(size_t)i * 4 + 3];
  }
  for (int off = 32; off > 0; off >>= 1) {
    v0 += __shfl_down(v0, off);
    v1 += __shfl_down(v1, off);
    v2 += __shfl_down(v2, off);
    v3 += __shfl_down(v3, off);
  }
  __shared__ double sred[THREADS / 64][4];
  const int wv = threadIdx.x >> 6;
  if ((threadIdx.x & 63) == 0) {
    sred[wv][0] = v0; sred[wv][1] = v1; sred[wv][2] = v2; sred[wv][3] = v3;
  }
  __syncthreads();
  if (threadIdx.x == 0) {
    double a0 = 0, a1 = 0, a2 = 0, a3 = 0;
#pragma unroll
    for (int w = 0; w < THREADS / 64; ++w) {
      a0 += sred[w][0]; a1 += sred[w][1]; a2 += sred[w][2]; a3 += sred[w][3];
    }
    double m = (double)mp[0];
    double n = (double)np_[0];
    double B = (double)Bp[0];
    out[0] = (float)((0.1 * (a0 + a1) / m + 0.6 * a2 / n + 0.2 * a3 / m) / B);
  }
}

// ---------------------------------------------------------------------------
// Dynamic-REP fallback (proven R3 path) for unexpected ws sizes.
// ---------------------------------------------------------------------------
__global__ void kkt_init(double* __restrict__ acc, float* __restrict__ out) {
  int t = threadIdx.x;
  if (t < 4) acc[t] = 0.0;
  if (t == 0) out[0] = 0.0f;
}

__global__ __launch_bounds__(SCAN_THREADS) void kkt_scan_dyn(
    const int* __restrict__ rows, const int* __restrict__ cols,
    const float* __restrict__ attr,
    const float* __restrict__ x, const float* __restrict__ lam,
    float* __restrict__ partial, int E, int REP) {
  __shared__ float lds[CSZ];
  const int p = blockIdx.x / REP;
  const int r = blockIdx.x % REP;
  const int baseM = p * CM;
  const int baseN = p * CN;
  vfloat4* l4 = (vfloat4*)lds;
  for (int i = threadIdx.x; i < CSZ / 4; i += SCAN_THREADS) l4[i] = (vfloat4)(0.0f);
  __syncthreads();
  long per = (((long)E + REP - 1) / REP + 3) & ~3L;
  long e0 = per * r;  if (e0 > E) e0 = E;
  long e1 = e0 + per; if (e1 > E) e1 = E;
  int  n4 = (int)((e1 - e0) >> 2);
  const vint4*   rows4 = (const vint4*)(rows + e0);
  const vint4*   cols4 = (const vint4*)(cols + e0);
  const vfloat4* attr4 = (const vfloat4*)(attr + e0);
#define EDGE_ACC(RR, CC, AA)                                                 \
  do {                                                                       \
    unsigned mm = (unsigned)((RR) - baseM);                                  \
    if (mm < (unsigned)CM) unsafeAtomicAdd(&lds[mm], (AA) * x[(CC)]);        \
    unsigned nn = (unsigned)((CC) - baseN);                                  \
    if (nn < (unsigned)CN) unsafeAtomicAdd(&lds[CM + nn], (AA) * lam[(RR)]); \
  } while (0)
  for (int i = threadIdx.x; i < n4; i += SCAN_THREADS) {
    vint4 rr = rows4[i]; vint4 cc = cols4[i]; vfloat4 aa = attr4[i];
    EDGE_ACC(rr.x, cc.x, aa.x);
    EDGE_ACC(rr.y, cc.y, aa.y);
    EDGE_ACC(rr.z, cc.z, aa.z);
    EDGE_ACC(rr.w, cc.w, aa.w);
  }
  for (long i = e0 + ((long)n4 << 2) + threadIdx.x; i < e1; i += SCAN_THREADS) {
    int rr = rows[i], cc = cols[i];
    float aa = attr[i];
    EDGE_ACC(rr, cc, aa);
  }
#undef EDGE_ACC
  __syncthreads();
  vfloat4* d4 = (vfloat4*)(partial + (size_t)(p * REP + r) * CSZ);
  for (int i = threadIdx.x; i < CSZ / 4; i += SCAN_THREADS) d4[i] = l4[i];
}

__global__ __launch_bounds__(THREADS) void kkt_loss_dyn(
    const float* __restrict__ partial,
    const float* __restrict__ bcat, const float* __restrict__ ccat,
    const float* __restrict__ lam, double* __restrict__ acc,
    int sum_m, int sum_n, int REP) {
  int idx = blockIdx.x * blockDim.x + threadIdx.x;
  int stride = gridDim.x * blockDim.x;
  double pr = 0.0, du = 0.0, st = 0.0, cs = 0.0;
  for (int i = idx; i < sum_m; i += stride) {
    int p = i / CM, j = i - p * CM;
    const float* base = partial + (size_t)(p * REP) * CSZ + j;
    float ax = 0.0f;
    for (int rr = 0; rr < REP; ++rr) ax += base[(size_t)rr * CSZ];
    float d  = ax - bcat[i];
    float li = lam[i];
    float pp   = d > 0.0f ? d : 0.0f;
    float u    = li < 0.0f ? -li : 0.0f;
    float comp = li * d;
    pr += (double)pp * pp;
    du += (double)u * u;
    cs += (double)comp * comp;
  }
  for (int i = idx; i < sum_n; i += stride) {
    int p = i / CN, j = i - p * CN;
    const float* base = partial + (size_t)(p * REP) * CSZ + CM + j;
    float at = 0.0f;
    for (int rr = 0; rr < REP; ++rr) at += base[(size_t)rr * CSZ];
    float s = at + ccat[i];
    st += (double)s * s;
  }
  for (int off = 32; off > 0; off >>= 1) {
    pr += __shfl_down(pr, off);
    du += __shfl_down(du, off);
    st += __shfl_down(st, off);
    cs += __shfl_down(cs, off);
  }
  if ((threadIdx.x & 63) == 0) {
    unsafeAtomicAdd(&acc[0], pr);
    unsafeAtomicAdd(&acc[1], du);
    unsafeAtomicAdd(&acc[2], st);
    unsafeAtomicAdd(&acc[3], cs);
  }
}

__global__ void kkt_finalize(const double* __restrict__ acc,
                             const int* __restrict__ Bp,
                             const int* __restrict__ mp,
                             const int* __restrict__ np_,
                             float* __restrict__ out) {
  double m = (double)mp[0];
  double n = (double)np_[0];
  double B = (double)Bp[0];
  double total =
      (0.1 * (acc[0] + acc[1]) / m + 0.6 * acc[2] / n + 0.2 * acc[3] / m) / B;
  out[0] = (float)total;
}

extern "C" void kernel_launch(void* const* d_in, const int* in_sizes, int n_in,
                              void* d_out, int out_size, void* d_ws, size_t ws_size,
                              hipStream_t stream) {
  const float* x    = (const float*)d_in[0];
  const float* lam  = (const float*)d_in[1];
  const int*   rows = (const int*)d_in[2];
  const int*   cols = (const int*)d_in[3];
  const float* attr = (const float*)d_in[4];
  const float* bcat = (const float*)d_in[5];
  const float* ccat = (const float*)d_in[6];
  const int*   Bp   = (const int*)d_in[7];
  const int*   mp   = (const int*)d_in[8];
  const int*   np_  = (const int*)d_in[9];

  const int sum_n = in_sizes[0];
  const int sum_m = in_sizes[1];
  const int E     = in_sizes[2];

  char*   ws   = (char*)d_ws;
  double* acc  = (double*)ws;                    // 32 B (fallback)
  double* bacc = (double*)(ws + 256);            // LOSS_BLOCKS*4 doubles
  float*  buf  = (float*)(ws + 256 + LOSS_BLOCKS * 4 * sizeof(double));
  float*  out  = (float*)d_out;

  const int NPr = (sum_m + CHUNK - 1) / CHUNK;
  const int NPc = (sum_n + CHUNK - 1) / CHUNK;
  const int NQ  = NPr + NPc;

  const size_t head = 256 + (size_t)LOSS_BLOCKS * 4 * sizeof(double);
  size_t avail = ws_size > head ? ws_size - head : 0;
  const size_t need_t = (size_t)NQ * REP_T * CHUNK * sizeof(float);

  if (avail >= need_t) {
    // fast path (measured best, R8 = 121.6 µs):
    // fused split row/col scan + atomic-free hierarchical reduction
    kkt_scan2_t<REP_T><<<NQ * REP_T, SCAN_THREADS, 0, stream>>>(
        rows, cols, attr, x, lam, buf, E, NPr);
    kkt_loss2_t<REP_T><<<LOSS_BLOCKS, THREADS, 0, stream>>>(
        buf, bcat, ccat, lam, bacc, sum_m, sum_n, NPr);
    kkt_finalize_fast<<<1, THREADS, 0, stream>>>(bacc, LOSS_BLOCKS, Bp, mp,
                                                 np_, out);
  } else {
    // proven R3-family fallback
    float* fbuf = (float*)(ws + 64);
    const int NPm = (sum_m + CM - 1) / CM;
    const int NPn = (sum_n + CN - 1) / CN;
    const int NP  = NPm > NPn ? NPm : NPn;
    size_t favail = ws_size > 64 ? ws_size - 64 : 0;
    int REP = (int)(favail / ((size_t)NP * CSZ * sizeof(float)));
    if (REP > MAX_REP) REP = MAX_REP;
    if (REP < 1) REP = 1;
    kkt_init<<<1, 64, 0, stream>>>(acc, out);
    kkt_scan_dyn<<<NP * REP, SCAN_THREADS, 0, stream>>>(rows, cols, attr, x,
                                                        lam, fbuf, E, REP);
    int lw = sum_m > sum_n ? sum_m : sum_n;
    int lb = (lw + THREADS - 1) / THREADS;
    if (lb > 1024) lb = 1024;
    kkt_loss_dyn<<<lb, THREADS, 0, stream>>>(fbuf, bcat, ccat, lam, acc,
                                             sum_m, sum_n, REP);
    kkt_finalize<<<1, 1, 0, stream>>>(acc, Bp, mp, np_, out);
  }
}